// Round 3
// baseline (492.811 us; speedup 1.0000x reference)
//
#include <hip/hip_runtime.h>

// AdditiveAttention on MI355X (gfx950)
// B=64, S=2048, D=512, U=512. All inputs fp32; output fp32 (B,D).
//
// R6: register rebalance in scorectx_k. R5 sat at exactly 128 regs/wave
// (64 AGPR acc + 64 VGPR) -> no room to prefetch the per-kstep B fragments,
// so every kstep stalled ~250cy on L2 latency (MfmaUtil 16%). Now each wave
// processes U in TWO temporal halves with acc[4][2] (32 AGPR), reducing
// scores into sAcc between halves; freed VGPRs fund an explicit one-kstep-
// ahead software pipeline of B (global) and A (LDS) fragments.
// launch_bounds (512,4) -> (512,2) (honest: LDS caps at 2 blocks/CU).

typedef __attribute__((ext_vector_type(8))) short bf16x8;
typedef __attribute__((ext_vector_type(4))) float f32x4;

#if __has_builtin(__builtin_amdgcn_exp2f)
__device__ __forceinline__ float fast_exp2(float x) { return __builtin_amdgcn_exp2f(x); }
#else
__device__ __forceinline__ float fast_exp2(float x) { return exp2f(x); }
#endif
#if __has_builtin(__builtin_amdgcn_rcpf)
__device__ __forceinline__ float fast_rcp(float x) { return __builtin_amdgcn_rcpf(x); }
#else
__device__ __forceinline__ float fast_rcp(float x) { return 1.0f / x; }
#endif

__device__ __forceinline__ unsigned short f2bf(float f) {
  unsigned int u = __float_as_uint(f);
  u += 0x7fffu + ((u >> 16) & 1u);
  return (unsigned short)(u >> 16);
}

// ---------------- k1: Q = query @ W1  (64x2 blocks x 256 thr) ---------------
__global__ void qk(const float* __restrict__ query, const float* __restrict__ W1,
                   float* __restrict__ Q) {
  __shared__ float qrow[512];
  const int b = blockIdx.x, half = blockIdx.y, t = threadIdx.x;
  qrow[t] = query[b * 512 + t];
  qrow[t + 256] = query[b * 512 + t + 256];
  __syncthreads();
  const int u = half * 256 + t;
  float acc = 0.f;
#pragma unroll 8
  for (int k = 0; k < 512; ++k) acc += qrow[k] * W1[(size_t)k * 512 + u];
  Q[b * 512 + u] = acc;
}

// ---------------- k2: Wtf = fragment-ordered bf16(W2^T) ---------------------
// Wtf[((ntile*16+ks)*64 + quad*16 + l15)*8 + j] = bf16(W2[ks*32+quad*8+j][ntile*16+l15])
__global__ void wt_k(const float* __restrict__ W2, unsigned short* __restrict__ Wtf) {
  const int gid = blockIdx.x * 256 + threadIdx.x;  // 0..32767
  const int lane = gid & 63;
  const int g = gid >> 6;  // ntile*16 + ks
  const int ks = g & 15, ntile = g >> 4;
  const int l15 = lane & 15, quad = lane >> 4;
  const int n = ntile * 16 + l15;
  const int k0 = ks * 32 + quad * 8;
  unsigned int p[4];
#pragma unroll
  for (int jj = 0; jj < 4; ++jj) {
    const float a = W2[(size_t)(k0 + 2 * jj) * 512 + n];
    const float b = W2[(size_t)(k0 + 2 * jj + 1) * 512 + n];
    p[jj] = (unsigned int)f2bf(a) | ((unsigned int)f2bf(b) << 16);
  }
  *(uint4*)&Wtf[(size_t)gid * 8] = make_uint4(p[0], p[1], p[2], p[3]);
}

// ---------------- k3: fused scores + split-softmax partial context ----------
// Block: 64 rows x full U=512, K=512. 8 waves. Wave w covers ntiles
// {nh*16 + w*2, nh*16 + w*2 + 1} in two temporal halves nh=0,1 (acc[4][2]
// reused across halves; score partials accumulate in sAcc via LDS atomics).
// A (values rows) -> bf16 LDS full-K, xor-swizzled 16B chunks (64KB).
// B fragments: contiguous 1KB wave loads from fragment-ordered Wtf (L2-res),
// software-pipelined one kstep ahead (as are the A LDS reads).
__global__ __launch_bounds__(512, 2) void scorectx_k(
    const float* __restrict__ values, const unsigned short* __restrict__ Wtf,
    const float* __restrict__ Q, const float* __restrict__ V1,
    float* __restrict__ Pstat, float* __restrict__ Pctx) {
  __shared__ __align__(16) unsigned short Ab[64 * 512];  // [m][512k], swizzled
  __shared__ float sAcc[64];
  __shared__ float wLDS[64];

  const int t = threadIdx.x;
  const int lane = t & 63;
  const int w = t >> 6;        // wave 0..7
  const int quad = lane >> 4;  // 0..3
  const int l15 = lane & 15;
  const int blk = blockIdx.x;
  const int m0 = blk * 64;
  const int b = m0 >> 11;  // /2048

  if (t < 64) sAcc[t] = 0.0f;

  // ---- stage A: 64 rows x 512 k, fp32 -> bf16, swizzled 16B chunks
  const float* Ag = values + (size_t)m0 * 512;
#pragma unroll
  for (int i = 0; i < 8; ++i) {
    const int c = i * 512 + t;  // chunk id: 64 rows x 64 chunks
    const int m = c >> 6;
    const int kc = c & 63;
    const float4* src = (const float4*)(Ag + (size_t)m * 512 + kc * 8);
    const float4 x = src[0], y = src[1];
    const unsigned int p0 = (unsigned int)f2bf(x.x) | ((unsigned int)f2bf(x.y) << 16);
    const unsigned int p1 = (unsigned int)f2bf(x.z) | ((unsigned int)f2bf(x.w) << 16);
    const unsigned int p2 = (unsigned int)f2bf(y.x) | ((unsigned int)f2bf(y.y) << 16);
    const unsigned int p3 = (unsigned int)f2bf(y.z) | ((unsigned int)f2bf(y.w) << 16);
    *(uint4*)&Ab[m * 512 + ((kc ^ (m & 7)) * 8)] = make_uint4(p0, p1, p2, p3);
  }
  __syncthreads();

  const int sw = l15 & 7;  // A swizzle key (m&7 == l15&7)
  const unsigned short* Blane = Wtf + (size_t)lane * 8;

#pragma unroll
  for (int nh = 0; nh < 2; ++nh) {
    const int t0 = nh * 16 + w * 2;  // ntile of nt=0 for this wave-half
    const unsigned short* B0 = Blane + (size_t)(t0 * 16) * 512;
    const unsigned short* B1 = Blane + (size_t)((t0 + 1) * 16) * 512;

    f32x4 acc[4][2];
#pragma unroll
    for (int mt = 0; mt < 4; ++mt) {
      acc[mt][0] = (f32x4){0.f, 0.f, 0.f, 0.f};
      acc[mt][1] = (f32x4){0.f, 0.f, 0.f, 0.f};
    }

    // prime the one-kstep-ahead pipeline (ks = 0)
    bf16x8 bc0 = *(const bf16x8*)B0;
    bf16x8 bc1 = *(const bf16x8*)B1;
    bf16x8 ac[4];
#pragma unroll
    for (int mt = 0; mt < 4; ++mt)
      ac[mt] = *(const bf16x8*)&Ab[(mt * 16 + l15) * 512 + ((quad ^ sw) * 8)];

#pragma unroll
    for (int ks = 0; ks < 16; ++ks) {
      bf16x8 bn0, bn1, an[4];
      if (ks < 15) {
        bn0 = *(const bf16x8*)(B0 + (size_t)(ks + 1) * 512);
        bn1 = *(const bf16x8*)(B1 + (size_t)(ks + 1) * 512);
#pragma unroll
        for (int mt = 0; mt < 4; ++mt)
          an[mt] = *(const bf16x8*)&Ab[(mt * 16 + l15) * 512 +
                                       ((((ks + 1) * 4 + quad) ^ sw) * 8)];
      }
#pragma unroll
      for (int mt = 0; mt < 4; ++mt) {
        acc[mt][0] = __builtin_amdgcn_mfma_f32_16x16x32_bf16(ac[mt], bc0, acc[mt][0], 0, 0, 0);
        acc[mt][1] = __builtin_amdgcn_mfma_f32_16x16x32_bf16(ac[mt], bc1, acc[mt][1], 0, 0, 0);
      }
      if (ks < 15) {
        bc0 = bn0;
        bc1 = bn1;
#pragma unroll
        for (int mt = 0; mt < 4; ++mt) ac[mt] = an[mt];
      }
    }

    // ---- epilogue (this half): part[m] += tanh(acc + Q[b,n]) * V1[n]
    // C/D layout: col(n) = lane&15, row(m within tile) = quad*4 + r
    float part[4][4];
#pragma unroll
    for (int mt = 0; mt < 4; ++mt)
#pragma unroll
      for (int r = 0; r < 4; ++r) part[mt][r] = 0.f;

#pragma unroll
    for (int nt = 0; nt < 2; ++nt) {
      const int n = (t0 + nt) * 16 + l15;
      const float qv = Q[b * 512 + n];
      const float v1 = V1[n];
#pragma unroll
      for (int mt = 0; mt < 4; ++mt)
#pragma unroll
        for (int r = 0; r < 4; ++r) {
          const float x = acc[mt][nt][r] + qv;
          const float e = fast_exp2(x * 2.8853900817779268f);  // e^{2x}
          const float th = 1.0f - 2.0f * fast_rcp(e + 1.0f);   // tanh(x)
          part[mt][r] += th * v1;
        }
    }
#pragma unroll
    for (int mt = 0; mt < 4; ++mt)
#pragma unroll
      for (int r = 0; r < 4; ++r) {
        float v = part[mt][r];
        v += __shfl_xor(v, 1);
        v += __shfl_xor(v, 2);
        v += __shfl_xor(v, 4);
        v += __shfl_xor(v, 8);
        if (l15 == 0) atomicAdd(&sAcc[mt * 16 + quad * 4 + r], v);
      }
  }
  __syncthreads();

  // ---- local softmax partials (wave 0: lanes 0..63 own the 64 rows)
  const float L2E = 1.4426950408889634f;
  if (t < 64) {
    const float v = sAcc[t];
    float m = v;
#pragma unroll
    for (int o = 1; o < 64; o <<= 1) m = fmaxf(m, __shfl_xor(m, o));
    const float wv = fast_exp2((v - m) * L2E);
    float dsum = wv;
#pragma unroll
    for (int o = 1; o < 64; o <<= 1) dsum += __shfl_xor(dsum, o);
    wLDS[t] = wv;
    if (t == 0) {
      Pstat[2 * blk] = m;
      Pstat[2 * blk + 1] = dsum;
    }
  }
  __syncthreads();

  // ---- partial context: thread t owns column u=t over the block's 64 rows.
  // fp32 re-read from global (rows just streamed -> mostly L2-hit).
  const float* vrow = values + (size_t)m0 * 512 + t;
  float cacc = 0.f;
#pragma unroll 8
  for (int r = 0; r < 64; ++r) cacc += wLDS[r] * vrow[(size_t)r * 512];
  Pctx[(size_t)blk * 512 + t] = cacc;
}

// ---------------- k4: combine partials ------------------------------------
// grid 64 (one per b) x 512 thr. 32 partials per b: global max M, denom
// D = sum d_i*exp(m_i-M); out[b,d] = sum_i ctx_i[d]*exp(m_i-M) / D. 4MB read.
__global__ __launch_bounds__(512) void comb_k(const float* __restrict__ Pstat,
                                              const float* __restrict__ Pctx,
                                              float* __restrict__ out) {
  __shared__ float aL[32];
  __shared__ float Dsh;
  const int b = blockIdx.x, t = threadIdx.x;
  const float L2E = 1.4426950408889634f;
  if (t < 32) {
    const float2 st = ((const float2*)Pstat)[b * 32 + t];
    float m = st.x;
#pragma unroll
    for (int o = 1; o < 32; o <<= 1) m = fmaxf(m, __shfl_xor(m, o));
    const float a = fast_exp2((st.x - m) * L2E);
    float D = a * st.y;
#pragma unroll
    for (int o = 1; o < 32; o <<= 1) D += __shfl_xor(D, o);
    aL[t] = a;
    if (t == 0) Dsh = D;
  }
  __syncthreads();
  const float* pc = Pctx + (size_t)b * 32 * 512 + t;
  float acc = 0.f;
#pragma unroll
  for (int i = 0; i < 32; ++i) acc += aL[i] * pc[(size_t)i * 512];
  out[b * 512 + t] = acc / Dsh;
}

extern "C" void kernel_launch(void* const* d_in, const int* in_sizes, int n_in,
                              void* d_out, int out_size, void* d_ws, size_t ws_size,
                              hipStream_t stream) {
  const float* query = (const float*)d_in[0];   // (64, 512)
  const float* values = (const float*)d_in[1];  // (64, 2048, 512)
  const float* W1 = (const float*)d_in[2];      // (512, 512)
  const float* W2 = (const float*)d_in[3];      // (512, 512)
  const float* V1 = (const float*)d_in[4];      // (512, 1)
  float* out = (float*)d_out;                   // (64, 512)

  char* ws = (char*)d_ws;
  float* Qp = (float*)ws;                                // 131072 B
  unsigned short* Wtp = (unsigned short*)(ws + 131072);  // 524288 B
  float* Pstat = (float*)(ws + 131072 + 524288);         // 16384 B (2048 x 2)
  float* Pctx = (float*)(ws + 131072 + 524288 + 16384);  // 4 MB (2048 x 512)

  qk<<<dim3(64, 2), 256, 0, stream>>>(query, W1, Qp);
  wt_k<<<128, 256, 0, stream>>>(W2, Wtp);
  scorectx_k<<<2048, 512, 0, stream>>>(values, Wtp, Qp, V1, Pstat, Pctx);
  comb_k<<<64, 512, 0, stream>>>(Pstat, Pctx, out);
}

// Round 6
// 476.969 us; speedup vs baseline: 1.0332x; 1.0332x over previous
//
#include <hip/hip_runtime.h>
#include <hip/hip_bf16.h>

// AdditiveAttention on MI355X (gfx950)
// B=64, S=2048, D=512, U=512. All inputs fp32; output fp32 (B,D).
//
// R8 (= R7 de-risked after two container failures): staging fp32->bf16 via
// HIP __float2bfloat16 pairs (RNE; compiler may fuse to v_cvt_pk_bf16_f32)
// instead of hand inline-asm. Structure = R5 (proven):
//  - scorectx_k: 64-row block, acc[4][4], 16 MFMA/kstep, split-softmax +
//    partial-context fusion.
//  - prep_k: qk + wt_k fused (4 -> 3 launches) to measure inter-launch gap.

typedef __attribute__((ext_vector_type(8))) short bf16x8;
typedef __attribute__((ext_vector_type(4))) float f32x4;

#if __has_builtin(__builtin_amdgcn_exp2f)
__device__ __forceinline__ float fast_exp2(float x) { return __builtin_amdgcn_exp2f(x); }
#else
__device__ __forceinline__ float fast_exp2(float x) { return exp2f(x); }
#endif
#if __has_builtin(__builtin_amdgcn_rcpf)
__device__ __forceinline__ float fast_rcp(float x) { return __builtin_amdgcn_rcpf(x); }
#else
__device__ __forceinline__ float fast_rcp(float x) { return 1.0f / x; }
#endif

__device__ __forceinline__ unsigned short f2bf(float f) {
  unsigned int u = __float_as_uint(f);
  u += 0x7fffu + ((u >> 16) & 1u);
  return (unsigned short)(u >> 16);
}

// pack two fp32 -> one dword of 2 bf16 (lo = a, hi = b), RNE via HIP intrinsics
__device__ __forceinline__ unsigned int cvt_pk_bf16(float a, float b) {
  const __hip_bfloat16 lo = __float2bfloat16(a);
  const __hip_bfloat16 hi = __float2bfloat16(b);
  const unsigned short ul = *reinterpret_cast<const unsigned short*>(&lo);
  const unsigned short uh = *reinterpret_cast<const unsigned short*>(&hi);
  return (unsigned int)ul | ((unsigned int)uh << 16);
}

// ---------------- k1: fused prep = qk (blocks 0..127) + wt_k (128..255) -----
// qk: Q = query @ W1, 64x2 sub-blocks x 256 thr.
// wt: Wtf fragment-ordered bf16(W2^T):
// Wtf[((ntile*16+ks)*64 + quad*16 + l15)*8 + j] = bf16(W2[ks*32+quad*8+j][ntile*16+l15])
__global__ __launch_bounds__(256) void prep_k(
    const float* __restrict__ query, const float* __restrict__ W1,
    const float* __restrict__ W2, float* __restrict__ Q,
    unsigned short* __restrict__ Wtf) {
  __shared__ float qrow[512];
  const int t = threadIdx.x;
  if (blockIdx.x < 128) {
    const int b = blockIdx.x >> 1, half = blockIdx.x & 1;
    qrow[t] = query[b * 512 + t];
    qrow[t + 256] = query[b * 512 + t + 256];
    __syncthreads();
    const int u = half * 256 + t;
    float acc = 0.f;
#pragma unroll 8
    for (int k = 0; k < 512; ++k) acc += qrow[k] * W1[(size_t)k * 512 + u];
    Q[b * 512 + u] = acc;
  } else {
    const int gid = (blockIdx.x - 128) * 256 + t;  // 0..32767
    const int lane = gid & 63;
    const int g = gid >> 6;  // ntile*16 + ks
    const int ks = g & 15, ntile = g >> 4;
    const int l15 = lane & 15, quad = lane >> 4;
    const int n = ntile * 16 + l15;
    const int k0 = ks * 32 + quad * 8;
    unsigned int p[4];
#pragma unroll
    for (int jj = 0; jj < 4; ++jj) {
      const float a = W2[(size_t)(k0 + 2 * jj) * 512 + n];
      const float b = W2[(size_t)(k0 + 2 * jj + 1) * 512 + n];
      p[jj] = (unsigned int)f2bf(a) | ((unsigned int)f2bf(b) << 16);
    }
    *(uint4*)&Wtf[(size_t)gid * 8] = make_uint4(p[0], p[1], p[2], p[3]);
  }
}

// ---------------- k2: fused scores + split-softmax partial context ----------
// Block: 64 rows x full U=512, K=512. 8 waves; wave w owns n-tiles w*4..w*4+3.
// A (values rows) -> bf16 LDS full-K, xor-swizzled 16B chunks (64KB).
// B fragments: contiguous 1KB wave loads from fragment-ordered Wtf (L2-res).
// Epilogue: tanh+V1 reduce -> 64 row scores in sAcc -> local softmax
// (m_i, d_i, w[64]) -> partial ctx column per thread (global fp32 re-read).
__global__ __launch_bounds__(512, 4) void scorectx_k(
    const float* __restrict__ values, const unsigned short* __restrict__ Wtf,
    const float* __restrict__ Q, const float* __restrict__ V1,
    float* __restrict__ Pstat, float* __restrict__ Pctx) {
  __shared__ __align__(16) unsigned short Ab[64 * 512];  // [m][512k], swizzled
  __shared__ float sAcc[64];
  __shared__ float wLDS[64];

  const int t = threadIdx.x;
  const int lane = t & 63;
  const int w = t >> 6;        // wave 0..7
  const int quad = lane >> 4;  // 0..3
  const int l15 = lane & 15;
  const int blk = blockIdx.x;
  const int m0 = blk * 64;
  const int b = m0 >> 11;  // /2048

  if (t < 64) sAcc[t] = 0.0f;

  // ---- stage A: 64 rows x 512 k, fp32 -> bf16 (RNE), swizzled 16B chunks
  const float* Ag = values + (size_t)m0 * 512;
#pragma unroll
  for (int i = 0; i < 8; ++i) {
    const int c = i * 512 + t;  // chunk id: 64 rows x 64 chunks
    const int m = c >> 6;
    const int kc = c & 63;
    const float4* src = (const float4*)(Ag + (size_t)m * 512 + kc * 8);
    const float4 x = src[0], y = src[1];
    const unsigned int p0 = cvt_pk_bf16(x.x, x.y);
    const unsigned int p1 = cvt_pk_bf16(x.z, x.w);
    const unsigned int p2 = cvt_pk_bf16(y.x, y.y);
    const unsigned int p3 = cvt_pk_bf16(y.z, y.w);
    *(uint4*)&Ab[m * 512 + ((kc ^ (m & 7)) * 8)] = make_uint4(p0, p1, p2, p3);
  }
  __syncthreads();

  f32x4 acc[4][4];
#pragma unroll
  for (int mt = 0; mt < 4; ++mt)
#pragma unroll
    for (int nt = 0; nt < 4; ++nt) acc[mt][nt] = (f32x4){0.f, 0.f, 0.f, 0.f};

  const unsigned short* Bg = Wtf + (size_t)lane * 8;  // + ((ntile*16+ks)*512)
  const int sw = l15 & 7;  // A swizzle key (m&7 == l15&7)

#pragma unroll
  for (int ks = 0; ks < 16; ++ks) {  // 16 k-steps of 32
    bf16x8 bfr[4], af[4];
#pragma unroll
    for (int nt = 0; nt < 4; ++nt)
      bfr[nt] = *(const bf16x8*)(Bg + (size_t)((w * 4 + nt) * 16 + ks) * 512);
#pragma unroll
    for (int mt = 0; mt < 4; ++mt) {
      const int m = mt * 16 + l15;
      af[mt] = *(const bf16x8*)&Ab[m * 512 + (((ks * 4 + quad) ^ sw) * 8)];
    }
#pragma unroll
    for (int mt = 0; mt < 4; ++mt)
#pragma unroll
      for (int nt = 0; nt < 4; ++nt)
        acc[mt][nt] = __builtin_amdgcn_mfma_f32_16x16x32_bf16(af[mt], bfr[nt],
                                                              acc[mt][nt], 0, 0, 0);
  }

  // ---- epilogue: part[m] += tanh(acc + Q[b,n]) * V1[n], reduce over n
  // C/D layout: col(n) = lane&15, row(m within tile) = quad*4 + r
  float part[4][4];
#pragma unroll
  for (int mt = 0; mt < 4; ++mt)
#pragma unroll
    for (int r = 0; r < 4; ++r) part[mt][r] = 0.f;

#pragma unroll
  for (int nt = 0; nt < 4; ++nt) {
    const int n = w * 64 + nt * 16 + l15;
    const float qv = Q[b * 512 + n];
    const float v1 = V1[n];
#pragma unroll
    for (int mt = 0; mt < 4; ++mt)
#pragma unroll
      for (int r = 0; r < 4; ++r) {
        const float x = acc[mt][nt][r] + qv;
        const float e = fast_exp2(x * 2.8853900817779268f);  // e^{2x}
        const float th = 1.0f - 2.0f * fast_rcp(e + 1.0f);   // tanh(x)
        part[mt][r] += th * v1;
      }
  }
#pragma unroll
  for (int mt = 0; mt < 4; ++mt)
#pragma unroll
    for (int r = 0; r < 4; ++r) {
      float v = part[mt][r];
      v += __shfl_xor(v, 1);
      v += __shfl_xor(v, 2);
      v += __shfl_xor(v, 4);
      v += __shfl_xor(v, 8);
      if (l15 == 0) atomicAdd(&sAcc[mt * 16 + quad * 4 + r], v);
    }
  __syncthreads();

  // ---- local softmax partials (wave 0: lanes 0..63 own the 64 rows)
  const float L2E = 1.4426950408889634f;
  if (t < 64) {
    const float v = sAcc[t];
    float m = v;
#pragma unroll
    for (int o = 1; o < 64; o <<= 1) m = fmaxf(m, __shfl_xor(m, o));
    const float wv = fast_exp2((v - m) * L2E);
    float dsum = wv;
#pragma unroll
    for (int o = 1; o < 64; o <<= 1) dsum += __shfl_xor(dsum, o);
    wLDS[t] = wv;
    if (t == 0) {
      Pstat[2 * blk] = m;
      Pstat[2 * blk + 1] = dsum;
    }
  }
  __syncthreads();

  // ---- partial context: thread t owns column u=t over the block's 64 rows.
  // fp32 re-read from global (rows just streamed -> mostly L2-hit).
  const float* vrow = values + (size_t)m0 * 512 + t;
  float cacc = 0.f;
#pragma unroll 8
  for (int r = 0; r < 64; ++r) cacc += wLDS[r] * vrow[(size_t)r * 512];
  Pctx[(size_t)blk * 512 + t] = cacc;
}

// ---------------- k3: combine partials ------------------------------------
// grid 64 (one per b) x 512 thr. 32 partials per b: global max M, denom
// D = sum d_i*exp(m_i-M); out[b,d] = sum_i ctx_i[d]*exp(m_i-M) / D. 4MB read.
__global__ __launch_bounds__(512) void comb_k(const float* __restrict__ Pstat,
                                              const float* __restrict__ Pctx,
                                              float* __restrict__ out) {
  __shared__ float aL[32];
  __shared__ float Dsh;
  const int b = blockIdx.x, t = threadIdx.x;
  const float L2E = 1.4426950408889634f;
  if (t < 32) {
    const float2 st = ((const float2*)Pstat)[b * 32 + t];
    float m = st.x;
#pragma unroll
    for (int o = 1; o < 32; o <<= 1) m = fmaxf(m, __shfl_xor(m, o));
    const float a = fast_exp2((st.x - m) * L2E);
    float D = a * st.y;
#pragma unroll
    for (int o = 1; o < 32; o <<= 1) D += __shfl_xor(D, o);
    aL[t] = a;
    if (t == 0) Dsh = D;
  }
  __syncthreads();
  const float* pc = Pctx + (size_t)b * 32 * 512 + t;
  float acc = 0.f;
#pragma unroll
  for (int i = 0; i < 32; ++i) acc += aL[i] * pc[(size_t)i * 512];
  out[b * 512 + t] = acc / Dsh;
}

extern "C" void kernel_launch(void* const* d_in, const int* in_sizes, int n_in,
                              void* d_out, int out_size, void* d_ws, size_t ws_size,
                              hipStream_t stream) {
  const float* query = (const float*)d_in[0];   // (64, 512)
  const float* values = (const float*)d_in[1];  // (64, 2048, 512)
  const float* W1 = (const float*)d_in[2];      // (512, 512)
  const float* W2 = (const float*)d_in[3];      // (512, 512)
  const float* V1 = (const float*)d_in[4];      // (512, 1)
  float* out = (float*)d_out;                   // (64, 512)

  char* ws = (char*)d_ws;
  float* Qp = (float*)ws;                                // 131072 B
  unsigned short* Wtp = (unsigned short*)(ws + 131072);  // 524288 B
  float* Pstat = (float*)(ws + 131072 + 524288);         // 16384 B (2048 x 2)
  float* Pctx = (float*)(ws + 131072 + 524288 + 16384);  // 4 MB (2048 x 512)

  prep_k<<<256, 256, 0, stream>>>(query, W1, W2, Qp, Wtp);
  scorectx_k<<<2048, 512, 0, stream>>>(values, Wtp, Qp, V1, Pstat, Pctx);
  comb_k<<<64, 512, 0, stream>>>(Pstat, Pctx, out);
}